// Round 9
// baseline (772.145 us; speedup 1.0000x reference)
//
#include <hip/hip_runtime.h>
#include <stdint.h>

#define DEV static __device__ __forceinline__

typedef __attribute__((ext_vector_type(8))) __bf16 bf16x8;   // MFMA A/B operand
typedef __attribute__((ext_vector_type(4))) float f32x4;     // MFMA C/D operand

DEV float bfs2f(unsigned short u) {
    union { unsigned int i; float f; } c; c.i = ((unsigned int)u) << 16; return c.f;
}
// f32 -> bf16 bits via HW converter (gfx950 v_cvt_pk_bf16_f32, RNE).
DEV unsigned short f2bf(float v) {
    union { __bf16 b; unsigned short u; } c; c.b = (__bf16)v; return c.u;
}

// ---------------------------------------------------------------------------
// GEMM: C(M,N) = A(M,K) @ B(N,K)^T [+bias+softplus]
// TH: block threads; waves 2 x (TH/128).
// AMODE/BMODE: 1 = pre-split hi/lo bf16 planes; 0 = raw fp32, HW-cvt split.
// 3 MFMA terms per 32-k: Ah*Bh + Al*Bh + Ah*Bl (~2^-17 rel).
// EPI: 0 none, 2 softplus(v+bias) clamp 60. CSPLIT: col>=ldc -> C1.
// grid.z = split-K slices (Klen each, partials at C0 + z*pstride).
// SWZ=1: z-per-XCD remap (lin%8 == XCD, HW-confirmed R7: FETCH 164->49 MB).
//   ONLY for gemm#1 (1 block/CU). R8: applying swizzles to the multi-
//   block/CU layer gemms REGRESSED ~27 us total — do not re-add.
// DBUF: single-barrier LDS double-buffer. R8: NEUTRAL on gemm#1 (80 us
//   either way; VALU overlap happened, wall time didn't move) — leave 0.
// gemm#1 status: 80 us vs 20.7 us MFMA floor after 3 structural levers
//   (tile, swizzle, dbuf). Remaining stall = load-latency/LDS path at
//   2 waves/SIMD (m97-structure ceiling). Next lever would be the 8-phase
//   counted-vmcnt rewrite — deferred (race-risk headless). PARKED.
// R5 lesson: scan is latency-bound at 1 wave/SIMD; dt-proj stays in MFMA.
// ---------------------------------------------------------------------------
template<int TH, int BM, int BN, int BK, int AMODE, int BMODE, int EPI,
         int CSPLIT, int SWZ, int DBUF>
__global__ __launch_bounds__(TH) void gemm_k(
    const void* __restrict__ A0, const void* __restrict__ A1,
    const void* __restrict__ B0, const void* __restrict__ B1,
    const float* __restrict__ bias,
    float* __restrict__ C0, float* __restrict__ C1,
    int lda, int ldb, int ldc, int Klen, int pstride)
{
    constexpr int NWN = TH / 128;                  // wave grid is 2 x NWN
    constexpr int FM = BM / 2 / 16;
    constexpr int FN = BN / NWN / 16;
    constexpr int KB = BK / 32;                    // 32-k sub-blocks per stage
    constexpr int GAF = (AMODE == 0) ? BM * BK / (TH * 4) : 1;  // float4/thread
    constexpr int GAP = (AMODE == 1) ? BM * BK / (TH * 8) : 1;  // int4-pairs/thread
    constexpr int GBF = (BMODE == 0) ? BN * BK / (TH * 4) : 1;
    constexpr int GBP = (BMODE == 1) ? BN * BK / (TH * 8) : 1;
    constexpr int BUFB = 2 * (BM + BN) * BK * 2;   // bytes per LDS stage buffer

    __shared__ __align__(16) char smem[(DBUF ? 2 : 1) * BUFB];

    int bx = blockIdx.x, by = blockIdx.y, bz = blockIdx.z;
    if (SWZ == 1) {
        int lin = blockIdx.x + gridDim.x * (blockIdx.y + gridDim.y * blockIdx.z);
        bz = lin & 7;                 // one split-K slice per XCD
        int rest = lin >> 3;
        bx = rest % gridDim.x;
        by = rest / gridDim.x;
    }

    const int tid = threadIdx.x, lane = tid & 63;
    const int wid = tid >> 6;
    const int wm = wid & 1, wn = wid >> 1;
    const int q = lane >> 4, t16 = lane & 15;
    const int tileM = bx * BM, tileN = by * BN;
    const int kBase = bz * Klen, kEnd = kBase + Klen;
    float* C = C0 + (size_t)bz * pstride;

    f32x4 acc[FM][FN];
#pragma unroll
    for (int a = 0; a < FM; ++a)
#pragma unroll
        for (int b = 0; b < FN; ++b) acc[a][b] = f32x4{0.f, 0.f, 0.f, 0.f};

    float4 aF[GAF], bF[GBF];
    int4 aH[GAP], aL[GAP], bH[GBP], bL[GBP];

    auto loadA = [&](int k0) {
        if (AMODE == 0) {
            const float* A32 = (const float*)A0;
#pragma unroll
            for (int u = 0; u < GAF; ++u) {
                int idx = u * TH + tid;
                int r = idx / (BK / 4), c4 = idx % (BK / 4);
                aF[u] = *(const float4*)(A32 + (size_t)(tileM + r) * lda + k0 + c4 * 4);
            }
        } else {
            const unsigned short* Ah = (const unsigned short*)A0;
            const unsigned short* Al = (const unsigned short*)A1;
#pragma unroll
            for (int u = 0; u < GAP; ++u) {
                int idx = u * TH + tid;
                int r = idx / (BK / 8), c8 = idx % (BK / 8);
                size_t src = (size_t)(tileM + r) * lda + k0 + c8 * 8;
                aH[u] = *(const int4*)(Ah + src);
                aL[u] = *(const int4*)(Al + src);
            }
        }
    };
    auto loadB = [&](int k0) {
        if (BMODE == 0) {
            const float* B32 = (const float*)B0;
#pragma unroll
            for (int u = 0; u < GBF; ++u) {
                int idx = u * TH + tid;
                int r = idx / (BK / 4), c4 = idx % (BK / 4);
                bF[u] = *(const float4*)(B32 + (size_t)(tileN + r) * ldb + k0 + c4 * 4);
            }
        } else {
            const unsigned short* Bh = (const unsigned short*)B0;
            const unsigned short* Bl = (const unsigned short*)B1;
#pragma unroll
            for (int u = 0; u < GBP; ++u) {
                int idx = u * TH + tid;
                int r = idx / (BK / 8), c8 = idx % (BK / 8);
                size_t src = (size_t)(tileN + r) * ldb + k0 + c8 * 8;
                bH[u] = *(const int4*)(Bh + src);
                bL[u] = *(const int4*)(Bl + src);
            }
        }
    };
    auto storeA = [&](char* sAh, char* sAl) {
        if (AMODE == 0) {
#pragma unroll
            for (int u = 0; u < GAF; ++u) {
                int idx = u * TH + tid;
                int r = idx / (BK / 4), c4 = idx % (BK / 4);
                float vv[4] = {aF[u].x, aF[u].y, aF[u].z, aF[u].w};
                ushort4 hv, lv;
                unsigned short* hp = (unsigned short*)&hv;
                unsigned short* lp = (unsigned short*)&lv;
#pragma unroll
                for (int e = 0; e < 4; ++e) {
                    unsigned short hb = f2bf(vv[e]);
                    hp[e] = hb; lp[e] = f2bf(vv[e] - bfs2f(hb));
                }
                int off = (c4 / 8) * BM * 64 + r * 64 + (c4 & 7) * 8;
                *(ushort4*)(sAh + off) = hv;
                *(ushort4*)(sAl + off) = lv;
            }
        } else {
#pragma unroll
            for (int u = 0; u < GAP; ++u) {
                int idx = u * TH + tid;
                int r = idx / (BK / 8), c8 = idx % (BK / 8);
                int off = (c8 / 4) * BM * 64 + r * 64 + (c8 & 3) * 16;
                *(int4*)(sAh + off) = aH[u];
                *(int4*)(sAl + off) = aL[u];
            }
        }
    };
    auto storeB = [&](char* sBh, char* sBl) {
        if (BMODE == 0) {
#pragma unroll
            for (int u = 0; u < GBF; ++u) {
                int idx = u * TH + tid;
                int r = idx / (BK / 4), c4 = idx % (BK / 4);
                float vv[4] = {bF[u].x, bF[u].y, bF[u].z, bF[u].w};
                ushort4 hv, lv;
                unsigned short* hp = (unsigned short*)&hv;
                unsigned short* lp = (unsigned short*)&lv;
#pragma unroll
                for (int e = 0; e < 4; ++e) {
                    unsigned short hb = f2bf(vv[e]);
                    hp[e] = hb; lp[e] = f2bf(vv[e] - bfs2f(hb));
                }
                int off = (c4 / 8) * BN * 64 + r * 64 + (c4 & 7) * 8;
                *(ushort4*)(sBh + off) = hv;
                *(ushort4*)(sBl + off) = lv;
            }
        } else {
#pragma unroll
            for (int u = 0; u < GBP; ++u) {
                int idx = u * TH + tid;
                int r = idx / (BK / 8), c8 = idx % (BK / 8);
                int off = (c8 / 4) * BN * 64 + r * 64 + (c8 & 3) * 16;
                *(int4*)(sBh + off) = bH[u];
                *(int4*)(sBl + off) = bL[u];
            }
        }
    };
    auto compute = [&](const char* sAh, const char* sAl,
                       const char* sBh, const char* sBl) {
#pragma unroll
        for (int kb = 0; kb < KB; ++kb) {
            bf16x8 ah[FM], al[FM], bh[FN], bl[FN];
#pragma unroll
            for (int fm = 0; fm < FM; ++fm) {
                int off = kb * BM * 64 + (wm * (BM / 2) + fm * 16 + t16) * 64 + q * 16;
                ah[fm] = *(const bf16x8*)(sAh + off);
                al[fm] = *(const bf16x8*)(sAl + off);
            }
#pragma unroll
            for (int fn = 0; fn < FN; ++fn) {
                int off = kb * BN * 64 + (wn * (BN / NWN) + fn * 16 + t16) * 64 + q * 16;
                bh[fn] = *(const bf16x8*)(sBh + off);
                bl[fn] = *(const bf16x8*)(sBl + off);
            }
#pragma unroll
            for (int fm = 0; fm < FM; ++fm)
#pragma unroll
                for (int fn = 0; fn < FN; ++fn) {
                    acc[fm][fn] = __builtin_amdgcn_mfma_f32_16x16x32_bf16(ah[fm], bh[fn], acc[fm][fn], 0, 0, 0);
                    acc[fm][fn] = __builtin_amdgcn_mfma_f32_16x16x32_bf16(al[fm], bh[fn], acc[fm][fn], 0, 0, 0);
                    acc[fm][fn] = __builtin_amdgcn_mfma_f32_16x16x32_bf16(ah[fm], bl[fn], acc[fm][fn], 0, 0, 0);
                }
        }
    };

    loadA(kBase); loadB(kBase);
    if (DBUF) {
        storeA(smem, smem + BM * BK * 2);
        storeB(smem + 2 * BM * BK * 2, smem + 2 * BM * BK * 2 + BN * BK * 2);
        __syncthreads();
        int p = 0;
        for (int k0 = kBase; k0 < kEnd; k0 += BK) {
            bool more = (k0 + BK < kEnd);
            if (more) { loadA(k0 + BK); loadB(k0 + BK); }
            char* cb = smem + p * BUFB;
            compute(cb, cb + BM * BK * 2,
                    cb + 2 * BM * BK * 2, cb + 2 * BM * BK * 2 + BN * BK * 2);
            if (more) {
                char* nb = smem + (p ^ 1) * BUFB;
                storeA(nb, nb + BM * BK * 2);
                storeB(nb + 2 * BM * BK * 2, nb + 2 * BM * BK * 2 + BN * BK * 2);
            }
            __syncthreads();
            p ^= 1;
        }
    } else {
        for (int k0 = kBase; k0 < kEnd; k0 += BK) {
            storeA(smem, smem + BM * BK * 2);
            storeB(smem + 2 * BM * BK * 2, smem + 2 * BM * BK * 2 + BN * BK * 2);
            __syncthreads();
            if (k0 + BK < kEnd) { loadA(k0 + BK); loadB(k0 + BK); }  // prefetch
            compute(smem, smem + BM * BK * 2,
                    smem + 2 * BM * BK * 2, smem + 2 * BM * BK * 2 + BN * BK * 2);
            __syncthreads();
        }
    }

    // ---- epilogue: C/D layout col=lane&15, row=(lane>>4)*4+reg  (m89/m91)
#pragma unroll
    for (int fm = 0; fm < FM; ++fm) {
        int row0 = tileM + wm * (BM / 2) + fm * 16 + q * 4;
#pragma unroll
        for (int fn = 0; fn < FN; ++fn) {
            int col = tileN + wn * (BN / NWN) + fn * 16 + t16;
            float* Cd = C; int cc2 = col;
            if (CSPLIT && col >= ldc) { Cd = C1; cc2 = col - ldc; }
            float bv = (EPI == 2) ? bias[col] : 0.f;
#pragma unroll
            for (int r = 0; r < 4; ++r) {
                float v = acc[fm][fn][r];
                if (EPI == 2) { v = fminf(v + bv, 60.f); v = log1pf(__expf(v)); }
                Cd[(size_t)(row0 + r) * ldc + cc2] = v;
            }
        }
    }
}

// ---------------------------------------------------------------------------
// reduce split-K partials (+bias) -> hi/lo planes (+ optional last-row fp32)
__global__ __launch_bounds__(256) void reduce_k(
    const float* __restrict__ part, int Z, int pstride, int n,
    const float* __restrict__ bias, int colmask,
    unsigned short* __restrict__ hi, unsigned short* __restrict__ lo,
    float* __restrict__ hlast, int colbits)
{
    int i = blockIdx.x * 256 + threadIdx.x;
    if (i >= n) return;
    float s = 0.f;
    for (int z = 0; z < Z; ++z) s += part[(size_t)z * pstride + i];
    if (bias) s += bias[i & colmask];
    unsigned short hb = f2bf(s);
    hi[i] = hb; lo[i] = f2bf(s - bfs2f(hb));
    if (hlast) {
        int row = i >> colbits;
        if ((row & 255) == 255)
            hlast[((row >> 8) << colbits) + (i & colmask)] = s;
    }
}

// causal depthwise conv (DC=4) + SiLU: xbuf(1024x1024) -> xc planes
__global__ __launch_bounds__(256) void conv_silu_k(
    const float* __restrict__ xb, const float* __restrict__ cw,
    const float* __restrict__ cb, unsigned short* __restrict__ xch,
    unsigned short* __restrict__ xcl)
{
    int i  = blockIdx.x * 256 + threadIdx.x;  // (bl, d)
    int d  = i & 1023;
    int bl = i >> 10;
    int l  = bl & 255;
    float a = cb[d];
#pragma unroll
    for (int k = 0; k < 4; ++k) {
        int ls = l + k - 3;
        if (ls >= 0) a += xb[(size_t)(bl + k - 3) * 1024 + d] * cw[d * 4 + k];
    }
    float v = a / (1.f + __expf(-a));
    unsigned short hb = f2bf(v);
    xch[i] = hb; xcl[i] = f2bf(v - bfs2f(hb));
}

// ---------------------------------------------------------------------------
// selective scan fused with +xc*D and *silu(z).  (R3-proven structure +
// R9 async-STAGE split, G15/T14: issue chunk c+1's global loads into
// registers BEFORE the 64-step compute of chunk c; convert+LDS-write after
// a post-compute barrier. Scan has zero TLP (1 wave/SIMD) so HBM latency
// was serial between barriers; now it hides under compute. Same loads,
// same arithmetic order -> bit-identical output. Barriers still 2/chunk.)
// 8 threads per channel (2 states each), 3-level shuffle reduce;
// 128 blocks = 4 b x 32 chunks of 32 ch.
__global__ __launch_bounds__(256) void scan_k(
    const float* __restrict__ zb,
    const unsigned short* __restrict__ xch, const unsigned short* __restrict__ xcl,
    const unsigned short* __restrict__ xdh, const unsigned short* __restrict__ xdl,
    const float* __restrict__ dt, const float* __restrict__ Alog,
    const float* __restrict__ Dp,
    unsigned short* __restrict__ ygh, unsigned short* __restrict__ ygl)
{
    __shared__ float sdt[2048], sxc[2048], szz[2048], sbc[2048];  // 32 KB
    int b   = blockIdx.x >> 5;
    int d0  = (blockIdx.x & 31) << 5;
    int ch  = threadIdx.x >> 3;           // channel within chunk (0..31)
    int d   = d0 + ch;
    int sub = threadIdx.x & 7;
    int j0  = sub * 2;                    // this thread's first state idx
    float An[2], hst[2] = {0.f, 0.f};
    An[0] = -__expf(Alog[d * 16 + j0]);
    An[1] = -__expf(Alog[d * 16 + j0 + 1]);
    float Dd  = Dp[d];
    int   bl0 = b * 256;

    // register staging buffers (issue-early / write-late)
    float rdt[8], rzz[8];
    unsigned short rxh[8], rxl[8], rbh[8], rbl[8];
    auto stage_load = [&](int c) {
#pragma unroll
        for (int it = 0; it < 8; ++it) {
            int j2 = it * 256 + threadIdx.x;
            int ll = j2 >> 5, dd = j2 & 31;
            size_t row = (size_t)(bl0 + c * 64 + ll);
            size_t gi  = row * 1024 + d0 + dd;
            rdt[it] = dt[gi];
            rxh[it] = xch[gi]; rxl[it] = xcl[gi];
            rzz[it] = zb[gi];
            size_t bi = row * 64 + 32 + dd;
            rbh[it] = xdh[bi]; rbl[it] = xdl[bi];
        }
    };
    auto stage_write = [&]() {
#pragma unroll
        for (int it = 0; it < 8; ++it) {
            int j2 = it * 256 + threadIdx.x;
            sdt[j2] = rdt[it];
            sxc[j2] = bfs2f(rxh[it]) + bfs2f(rxl[it]);
            szz[j2] = rzz[it];
            sbc[j2] = bfs2f(rbh[it]) + bfs2f(rbl[it]);
        }
    };

    stage_load(0);
    stage_write();
    __syncthreads();
    for (int c = 0; c < 4; ++c) {
        if (c < 3) stage_load(c + 1);     // loads in flight during compute
#pragma unroll 4
        for (int li = 0; li < 64; ++li) {
            float dtv = sdt[li * 32 + ch];
            float xcv = sxc[li * 32 + ch];
            float c1  = dtv * xcv;
            float dA0 = __expf(dtv * An[0]);
            float dA1 = __expf(dtv * An[1]);
            float B0  = sbc[li * 32 + j0],      B1 = sbc[li * 32 + j0 + 1];
            float C0  = sbc[li * 32 + 16 + j0], C1 = sbc[li * 32 + 16 + j0 + 1];
            hst[0] = dA0 * hst[0] + c1 * B0;
            hst[1] = dA1 * hst[1] + c1 * B1;
            float y = hst[0] * C0 + hst[1] * C1;
            y += __shfl_xor(y, 1);
            y += __shfl_xor(y, 2);
            y += __shfl_xor(y, 4);
            if (sub == 0) {
                float zv = szz[li * 32 + ch];
                float sg = zv / (1.f + __expf(-zv));
                float v  = (y + xcv * Dd) * sg;
                unsigned short hb = f2bf(v);
                size_t o = (size_t)(bl0 + c * 64 + li) * 1024 + d;
                ygh[o] = hb; ygl[o] = f2bf(v - bfs2f(hb));
            }
        }
        if (c < 3) {
            __syncthreads();              // all reads of chunk c done
            stage_write();                // write chunk c+1 into LDS
            __syncthreads();              // visible before next compute
        }
    }
}

// ---------------------------------------------------------------------------
// LayerNorm of hlast (4 x 512) -> hn
__global__ __launch_bounds__(512) void ln_k(
    const float* __restrict__ hlast, const float* __restrict__ g,
    const float* __restrict__ bb, float* __restrict__ hn)
{
    __shared__ float red[16];
    int b = blockIdx.x, k = threadIdx.x;
    float x = hlast[b * 512 + k];
    float s = x, s2 = x * x;
#pragma unroll
    for (int m = 32; m; m >>= 1) { s += __shfl_xor(s, m, 64); s2 += __shfl_xor(s2, m, 64); }
    if ((k & 63) == 0) { red[k >> 6] = s; red[8 + (k >> 6)] = s2; }
    __syncthreads();
    float ts = 0.f, ts2 = 0.f;
#pragma unroll
    for (int j = 0; j < 8; ++j) { ts += red[j]; ts2 += red[8 + j]; }
    float mu   = ts * (1.f / 512.f);
    float var  = ts2 * (1.f / 512.f) - mu * mu;
    float rstd = rsqrtf(var + 1e-5f);
    hn[b * 512 + k] = (x - mu) * rstd * g[k] + bb[k];
}

// final: out(4,16384) = hn(4,512) @ out_w(16384,512)^T + out_b  (fp32)
__global__ __launch_bounds__(256) void final_k(
    const float* __restrict__ hn, const float* __restrict__ W,
    const float* __restrict__ ob, float* __restrict__ out)
{
    int wid = threadIdx.x >> 6, lane = threadIdx.x & 63;
    float a[4][8];
#pragma unroll
    for (int b2 = 0; b2 < 4; ++b2) {
        float4 v0 = *(const float4*)&hn[b2 * 512 + lane * 8];
        float4 v1 = *(const float4*)&hn[b2 * 512 + lane * 8 + 4];
        a[b2][0] = v0.x; a[b2][1] = v0.y; a[b2][2] = v0.z; a[b2][3] = v0.w;
        a[b2][4] = v1.x; a[b2][5] = v1.y; a[b2][6] = v1.z; a[b2][7] = v1.w;
    }
#pragma unroll 1
    for (int it = 0; it < 8; ++it) {
        int n = blockIdx.x * 4 + wid + it * 2048;
        const float* W32 = W + (size_t)n * 512 + lane * 8;
        float4 v0 = *(const float4*)W32;
        float4 v1 = *(const float4*)(W32 + 4);
        float wf[8] = {v0.x, v0.y, v0.z, v0.w, v1.x, v1.y, v1.z, v1.w};
        float s0 = 0.f, s1 = 0.f, s2 = 0.f, s3 = 0.f;
#pragma unroll
        for (int j = 0; j < 8; ++j) {
            s0 += a[0][j] * wf[j]; s1 += a[1][j] * wf[j];
            s2 += a[2][j] * wf[j]; s3 += a[3][j] * wf[j];
        }
#pragma unroll
        for (int m = 32; m; m >>= 1) {
            s0 += __shfl_xor(s0, m, 64); s1 += __shfl_xor(s1, m, 64);
            s2 += __shfl_xor(s2, m, 64); s3 += __shfl_xor(s3, m, 64);
        }
        if (lane == 0) {
            float bv = ob[n];
            out[0 * 16384 + n] = s0 + bv;
            out[1 * 16384 + n] = s1 + bv;
            out[2 * 16384 + n] = s2 + bv;
            out[3 * 16384 + n] = s3 + bv;
        }
    }
}

// ---------------------------------------------------------------------------
extern "C" void kernel_launch(void* const* d_in, const int* in_sizes, int n_in,
                              void* d_out, int out_size, void* d_ws, size_t ws_size,
                              hipStream_t stream)
{
    const float* x      = (const float*)d_in[0];
    const float* in_w   = (const float*)d_in[1];
    const float* in_b   = (const float*)d_in[2];
    const float* ln_g   = (const float*)d_in[3];
    const float* ln_b   = (const float*)d_in[4];
    const float* out_w  = (const float*)d_in[5];
    const float* out_b  = (const float*)d_in[6];
    const float* m_in_w = (const float*)d_in[7];
    const float* conv_w = (const float*)d_in[8];
    const float* conv_b = (const float*)d_in[9];
    const float* xproj_w= (const float*)d_in[10];
    const float* dt_w   = (const float*)d_in[11];
    const float* dt_b   = (const float*)d_in[12];
    const float* A_log  = (const float*)d_in[13];
    const float* D_p    = (const float*)d_in[14];
    const float* m_out_w= (const float*)d_in[15];

    // ---- ws layout, peak 22.1 MB (< proven-safe 23.3 MB) ----
    char* W = (char*)d_ws;
    unsigned short* hplh = (unsigned short*)(W + 0);          // h hi  1 MB
    unsigned short* hpll = (unsigned short*)(W + 1048576);    // h lo  1 MB
    float* hlast = (float*)(W + 2097152);                     // 8 KB
    float* hn    = (float*)(W + 2162688);                     // 8 KB
    float* xbuf  = (float*)(W + 2228224);                     // 4 MB
    float* zbuf  = (float*)(W + 6422528);                     // 4 MB
    unsigned short* xch = (unsigned short*)(W + 10616832);    // 2 MB
    unsigned short* xcl = (unsigned short*)(W + 12713984);    // 2 MB
    float* dtb   = (float*)(W + 14811136);                    // 4 MB
    unsigned short* xdbh  = (unsigned short*)(W + 19005440);  // 128 KB
    unsigned short* xdbl_ = (unsigned short*)(W + 19136512);  // 128 KB
    // aliases (sequencing-safe):
    float* part1 = (float*)(W + 2228224);                     // 16 MB, pre-layer only
    float* partx = (float*)(W + 14811136);                    // 4 MB (16 slices), dead before dtb written
    float* parto = (float*)(W + 6422528);                     // 16 MB (8 slices) over zbuf+xc+dtb+xdb (all dead post-scan)
    unsigned short* ygh = (unsigned short*)(W + 2228224);     // 2 MB over xbuf (dead post-conv)
    unsigned short* ygl = (unsigned short*)(W + 4325376);     // 2 MB

    // h = x @ in_w.T + in_b   (split-K=8; 128x128 tile, 512 threads;
    // SWZ=1 z-per-XCD; DBUF=0 — R8 showed dbuf neutral, swizzle-on-layer
    // gemms harmful. This exact config measured ~80 us in R7.)
    gemm_k<512,128,128,64,0,0,0,0,1,0><<<dim3(8,4,8),512,0,stream>>>(
        x, nullptr, in_w, nullptr, nullptr, part1, nullptr,
        16384, 16384, 512, 2048, 524288);
    reduce_k<<<2048,256,0,stream>>>(part1, 8, 524288, 524288, in_b, 511,
                                    hplh, hpll, hlast, 9);

    for (int i = 0; i < 4; ++i) {
        const float* iw = m_in_w  + (size_t)i * 1048576;
        const float* cw = conv_w  + (size_t)i * 4096;
        const float* cb = conv_b  + (size_t)i * 1024;
        const float* xw = xproj_w + (size_t)i * 65536;
        const float* dw = dt_w    + (size_t)i * 32768;
        const float* db = dt_b    + (size_t)i * 1024;
        const float* Al = A_log   + (size_t)i * 16384;
        const float* Dp = D_p     + (size_t)i * 1024;
        const float* ow = m_out_w + (size_t)i * 524288;

        // xz = h @ iw.T  (1024x2048, K=512) -> xbuf | zbuf  (R6 config)
        gemm_k<512,64,128,64,1,0,0,1,0,0><<<dim3(16,16,1),512,0,stream>>>(
            hplh, hpll, iw, nullptr, nullptr, xbuf, zbuf, 512, 512, 1024, 512, 0);
        // xc = silu(causal_conv(xbuf)) -> planes
        conv_silu_k<<<4096,256,0,stream>>>(xbuf, cw, cb, xch, xcl);
        // xdbl = xc @ xw.T  (1024x64, K=1024, split-K=16 -> 256 blocks)
        gemm_k<256,64,64,64,1,0,0,0,0,0><<<dim3(16,1,16),256,0,stream>>>(
            xch, xcl, xw, nullptr, nullptr, partx, nullptr, 1024, 1024, 64, 64, 65536);
        reduce_k<<<256,256,0,stream>>>(partx, 16, 65536, 65536, nullptr, 63,
                                       xdbh, xdbl_, nullptr, 6);
        // dt = softplus(xdbl[:, :32] @ dw.T + db)  (1024x1024, K=32, 256 blocks)
        gemm_k<256,64,64,32,1,0,2,0,0,0><<<dim3(16,16,1),256,0,stream>>>(
            xdbh, xdbl_, dw, nullptr, db, dtb, nullptr, 64, 32, 1024, 32, 0);
        // yg = (scan + xc*D) * silu(z) -> planes (128 blocks, async-staged)
        scan_k<<<128,256,0,stream>>>(zbuf, xch, xcl, xdbh, xdbl_, dtb, Al, Dp,
                                     ygh, ygl);
        // h = yg @ ow.T  (1024x512, K=1024, split-K=8 -> 512 blocks, R6 config)
        gemm_k<512,64,128,64,1,0,0,0,0,0><<<dim3(16,4,8),512,0,stream>>>(
            ygh, ygl, ow, nullptr, nullptr, parto, nullptr, 1024, 1024, 512, 128, 524288);
        reduce_k<<<2048,256,0,stream>>>(parto, 8, 524288, 524288, nullptr, 511,
                                        hplh, hpll, hlast, 9);
    }

    ln_k<<<4,512,0,stream>>>(hlast, ln_g, ln_b, hn);
    final_k<<<512,256,0,stream>>>(hn, out_w, out_b, (float*)d_out);
}

// Round 10
// 697.082 us; speedup vs baseline: 1.1077x; 1.1077x over previous
//
#include <hip/hip_runtime.h>
#include <stdint.h>

#define DEV static __device__ __forceinline__

typedef __attribute__((ext_vector_type(8))) __bf16 bf16x8;   // MFMA A/B operand
typedef __attribute__((ext_vector_type(4))) float f32x4;     // MFMA C/D operand

DEV float bfs2f(unsigned short u) {
    union { unsigned int i; float f; } c; c.i = ((unsigned int)u) << 16; return c.f;
}
// f32 -> bf16 bits via HW converter (gfx950 v_cvt_pk_bf16_f32, RNE).
DEV unsigned short f2bf(float v) {
    union { __bf16 b; unsigned short u; } c; c.b = (__bf16)v; return c.u;
}

// ---------------------------------------------------------------------------
// GEMM: C(M,N) = A(M,K) @ B(N,K)^T [+bias+softplus]
// TH: block threads; waves 2 x (TH/128).
// AMODE/BMODE: 1 = pre-split hi/lo bf16 planes; 0 = raw fp32, HW-cvt split.
// 3 MFMA terms per 32-k: Ah*Bh + Al*Bh + Ah*Bl (~2^-17 rel).
// EPI: 0 none, 2 softplus(v+bias) clamp 60. CSPLIT: col>=ldc -> C1.
// grid.z = split-K slices (Klen each, partials at C0 + z*pstride).
// SWZ=1: z-per-XCD remap (lin%8 == XCD, HW-confirmed R7: FETCH 164->49 MB).
//   ONLY for gemm#1. R8: swizzles on multi-block/CU layer gemms REGRESSED.
// DBUF: single-barrier LDS double-buffer — neutral on gemm#1 (R8 vs R7/R9
//   within the +-5% noise band); leave 0.
// gemm#1 status: ~80-85 us vs 20.7 us MFMA floor after 3 structural levers
//   (tile, swizzle, dbuf). Remaining stall = load-latency/LDS path at
//   2 waves/SIMD (m97-structure ceiling). PARKED (8-phase rewrite is the
//   next lever; race-risk headless).
// R5 lesson: scan is latency-bound at 1 wave/SIMD; dt-proj stays in MFMA.
// R9 lesson: reg-staged async-STAGE in scan regressed (+8 us/dispatch) —
//   48 live regs across the serial loop; T14 needs a long compute phase.
// ---------------------------------------------------------------------------
template<int TH, int BM, int BN, int BK, int AMODE, int BMODE, int EPI,
         int CSPLIT, int SWZ, int DBUF>
__global__ __launch_bounds__(TH) void gemm_k(
    const void* __restrict__ A0, const void* __restrict__ A1,
    const void* __restrict__ B0, const void* __restrict__ B1,
    const float* __restrict__ bias,
    float* __restrict__ C0, float* __restrict__ C1,
    int lda, int ldb, int ldc, int Klen, int pstride)
{
    constexpr int NWN = TH / 128;                  // wave grid is 2 x NWN
    constexpr int FM = BM / 2 / 16;
    constexpr int FN = BN / NWN / 16;
    constexpr int KB = BK / 32;                    // 32-k sub-blocks per stage
    constexpr int GAF = (AMODE == 0) ? BM * BK / (TH * 4) : 1;  // float4/thread
    constexpr int GAP = (AMODE == 1) ? BM * BK / (TH * 8) : 1;  // int4-pairs/thread
    constexpr int GBF = (BMODE == 0) ? BN * BK / (TH * 4) : 1;
    constexpr int GBP = (BMODE == 1) ? BN * BK / (TH * 8) : 1;
    constexpr int BUFB = 2 * (BM + BN) * BK * 2;   // bytes per LDS stage buffer

    __shared__ __align__(16) char smem[(DBUF ? 2 : 1) * BUFB];

    int bx = blockIdx.x, by = blockIdx.y, bz = blockIdx.z;
    if (SWZ == 1) {
        int lin = blockIdx.x + gridDim.x * (blockIdx.y + gridDim.y * blockIdx.z);
        bz = lin & 7;                 // one split-K slice per XCD
        int rest = lin >> 3;
        bx = rest % gridDim.x;
        by = rest / gridDim.x;
    }

    const int tid = threadIdx.x, lane = tid & 63;
    const int wid = tid >> 6;
    const int wm = wid & 1, wn = wid >> 1;
    const int q = lane >> 4, t16 = lane & 15;
    const int tileM = bx * BM, tileN = by * BN;
    const int kBase = bz * Klen, kEnd = kBase + Klen;
    float* C = C0 + (size_t)bz * pstride;

    f32x4 acc[FM][FN];
#pragma unroll
    for (int a = 0; a < FM; ++a)
#pragma unroll
        for (int b = 0; b < FN; ++b) acc[a][b] = f32x4{0.f, 0.f, 0.f, 0.f};

    float4 aF[GAF], bF[GBF];
    int4 aH[GAP], aL[GAP], bH[GBP], bL[GBP];

    auto loadA = [&](int k0) {
        if (AMODE == 0) {
            const float* A32 = (const float*)A0;
#pragma unroll
            for (int u = 0; u < GAF; ++u) {
                int idx = u * TH + tid;
                int r = idx / (BK / 4), c4 = idx % (BK / 4);
                aF[u] = *(const float4*)(A32 + (size_t)(tileM + r) * lda + k0 + c4 * 4);
            }
        } else {
            const unsigned short* Ah = (const unsigned short*)A0;
            const unsigned short* Al = (const unsigned short*)A1;
#pragma unroll
            for (int u = 0; u < GAP; ++u) {
                int idx = u * TH + tid;
                int r = idx / (BK / 8), c8 = idx % (BK / 8);
                size_t src = (size_t)(tileM + r) * lda + k0 + c8 * 8;
                aH[u] = *(const int4*)(Ah + src);
                aL[u] = *(const int4*)(Al + src);
            }
        }
    };
    auto loadB = [&](int k0) {
        if (BMODE == 0) {
            const float* B32 = (const float*)B0;
#pragma unroll
            for (int u = 0; u < GBF; ++u) {
                int idx = u * TH + tid;
                int r = idx / (BK / 4), c4 = idx % (BK / 4);
                bF[u] = *(const float4*)(B32 + (size_t)(tileN + r) * ldb + k0 + c4 * 4);
            }
        } else {
            const unsigned short* Bh = (const unsigned short*)B0;
            const unsigned short* Bl = (const unsigned short*)B1;
#pragma unroll
            for (int u = 0; u < GBP; ++u) {
                int idx = u * TH + tid;
                int r = idx / (BK / 8), c8 = idx % (BK / 8);
                size_t src = (size_t)(tileN + r) * ldb + k0 + c8 * 8;
                bH[u] = *(const int4*)(Bh + src);
                bL[u] = *(const int4*)(Bl + src);
            }
        }
    };
    auto storeA = [&](char* sAh, char* sAl) {
        if (AMODE == 0) {
#pragma unroll
            for (int u = 0; u < GAF; ++u) {
                int idx = u * TH + tid;
                int r = idx / (BK / 4), c4 = idx % (BK / 4);
                float vv[4] = {aF[u].x, aF[u].y, aF[u].z, aF[u].w};
                ushort4 hv, lv;
                unsigned short* hp = (unsigned short*)&hv;
                unsigned short* lp = (unsigned short*)&lv;
#pragma unroll
                for (int e = 0; e < 4; ++e) {
                    unsigned short hb = f2bf(vv[e]);
                    hp[e] = hb; lp[e] = f2bf(vv[e] - bfs2f(hb));
                }
                int off = (c4 / 8) * BM * 64 + r * 64 + (c4 & 7) * 8;
                *(ushort4*)(sAh + off) = hv;
                *(ushort4*)(sAl + off) = lv;
            }
        } else {
#pragma unroll
            for (int u = 0; u < GAP; ++u) {
                int idx = u * TH + tid;
                int r = idx / (BK / 8), c8 = idx % (BK / 8);
                int off = (c8 / 4) * BM * 64 + r * 64 + (c8 & 3) * 16;
                *(int4*)(sAh + off) = aH[u];
                *(int4*)(sAl + off) = aL[u];
            }
        }
    };
    auto storeB = [&](char* sBh, char* sBl) {
        if (BMODE == 0) {
#pragma unroll
            for (int u = 0; u < GBF; ++u) {
                int idx = u * TH + tid;
                int r = idx / (BK / 4), c4 = idx % (BK / 4);
                float vv[4] = {bF[u].x, bF[u].y, bF[u].z, bF[u].w};
                ushort4 hv, lv;
                unsigned short* hp = (unsigned short*)&hv;
                unsigned short* lp = (unsigned short*)&lv;
#pragma unroll
                for (int e = 0; e < 4; ++e) {
                    unsigned short hb = f2bf(vv[e]);
                    hp[e] = hb; lp[e] = f2bf(vv[e] - bfs2f(hb));
                }
                int off = (c4 / 8) * BN * 64 + r * 64 + (c4 & 7) * 8;
                *(ushort4*)(sBh + off) = hv;
                *(ushort4*)(sBl + off) = lv;
            }
        } else {
#pragma unroll
            for (int u = 0; u < GBP; ++u) {
                int idx = u * TH + tid;
                int r = idx / (BK / 8), c8 = idx % (BK / 8);
                int off = (c8 / 4) * BN * 64 + r * 64 + (c8 & 3) * 16;
                *(int4*)(sBh + off) = bH[u];
                *(int4*)(sBl + off) = bL[u];
            }
        }
    };
    auto compute = [&](const char* sAh, const char* sAl,
                       const char* sBh, const char* sBl) {
#pragma unroll
        for (int kb = 0; kb < KB; ++kb) {
            bf16x8 ah[FM], al[FM], bh[FN], bl[FN];
#pragma unroll
            for (int fm = 0; fm < FM; ++fm) {
                int off = kb * BM * 64 + (wm * (BM / 2) + fm * 16 + t16) * 64 + q * 16;
                ah[fm] = *(const bf16x8*)(sAh + off);
                al[fm] = *(const bf16x8*)(sAl + off);
            }
#pragma unroll
            for (int fn = 0; fn < FN; ++fn) {
                int off = kb * BN * 64 + (wn * (BN / NWN) + fn * 16 + t16) * 64 + q * 16;
                bh[fn] = *(const bf16x8*)(sBh + off);
                bl[fn] = *(const bf16x8*)(sBl + off);
            }
#pragma unroll
            for (int fm = 0; fm < FM; ++fm)
#pragma unroll
                for (int fn = 0; fn < FN; ++fn) {
                    acc[fm][fn] = __builtin_amdgcn_mfma_f32_16x16x32_bf16(ah[fm], bh[fn], acc[fm][fn], 0, 0, 0);
                    acc[fm][fn] = __builtin_amdgcn_mfma_f32_16x16x32_bf16(al[fm], bh[fn], acc[fm][fn], 0, 0, 0);
                    acc[fm][fn] = __builtin_amdgcn_mfma_f32_16x16x32_bf16(ah[fm], bl[fn], acc[fm][fn], 0, 0, 0);
                }
        }
    };

    loadA(kBase); loadB(kBase);
    if (DBUF) {
        storeA(smem, smem + BM * BK * 2);
        storeB(smem + 2 * BM * BK * 2, smem + 2 * BM * BK * 2 + BN * BK * 2);
        __syncthreads();
        int p = 0;
        for (int k0 = kBase; k0 < kEnd; k0 += BK) {
            bool more = (k0 + BK < kEnd);
            if (more) { loadA(k0 + BK); loadB(k0 + BK); }
            char* cb = smem + p * BUFB;
            compute(cb, cb + BM * BK * 2,
                    cb + 2 * BM * BK * 2, cb + 2 * BM * BK * 2 + BN * BK * 2);
            if (more) {
                char* nb = smem + (p ^ 1) * BUFB;
                storeA(nb, nb + BM * BK * 2);
                storeB(nb + 2 * BM * BK * 2, nb + 2 * BM * BK * 2 + BN * BK * 2);
            }
            __syncthreads();
            p ^= 1;
        }
    } else {
        for (int k0 = kBase; k0 < kEnd; k0 += BK) {
            storeA(smem, smem + BM * BK * 2);
            storeB(smem + 2 * BM * BK * 2, smem + 2 * BM * BK * 2 + BN * BK * 2);
            __syncthreads();
            if (k0 + BK < kEnd) { loadA(k0 + BK); loadB(k0 + BK); }  // prefetch
            compute(smem, smem + BM * BK * 2,
                    smem + 2 * BM * BK * 2, smem + 2 * BM * BK * 2 + BN * BK * 2);
            __syncthreads();
        }
    }

    // ---- epilogue: C/D layout col=lane&15, row=(lane>>4)*4+reg  (m89/m91)
#pragma unroll
    for (int fm = 0; fm < FM; ++fm) {
        int row0 = tileM + wm * (BM / 2) + fm * 16 + q * 4;
#pragma unroll
        for (int fn = 0; fn < FN; ++fn) {
            int col = tileN + wn * (BN / NWN) + fn * 16 + t16;
            float* Cd = C; int cc2 = col;
            if (CSPLIT && col >= ldc) { Cd = C1; cc2 = col - ldc; }
            float bv = (EPI == 2) ? bias[col] : 0.f;
#pragma unroll
            for (int r = 0; r < 4; ++r) {
                float v = acc[fm][fn][r];
                if (EPI == 2) { v = fminf(v + bv, 60.f); v = log1pf(__expf(v)); }
                Cd[(size_t)(row0 + r) * ldc + cc2] = v;
            }
        }
    }
}

// ---------------------------------------------------------------------------
// reduce split-K partials (+bias) -> hi/lo planes (+ optional last-row fp32)
__global__ __launch_bounds__(256) void reduce_k(
    const float* __restrict__ part, int Z, int pstride, int n,
    const float* __restrict__ bias, int colmask,
    unsigned short* __restrict__ hi, unsigned short* __restrict__ lo,
    float* __restrict__ hlast, int colbits)
{
    int i = blockIdx.x * 256 + threadIdx.x;
    if (i >= n) return;
    float s = 0.f;
    for (int z = 0; z < Z; ++z) s += part[(size_t)z * pstride + i];
    if (bias) s += bias[i & colmask];
    unsigned short hb = f2bf(s);
    hi[i] = hb; lo[i] = f2bf(s - bfs2f(hb));
    if (hlast) {
        int row = i >> colbits;
        if ((row & 255) == 255)
            hlast[((row >> 8) << colbits) + (i & colmask)] = s;
    }
}

// causal depthwise conv (DC=4) + SiLU: xbuf(1024x1024) -> xc planes
__global__ __launch_bounds__(256) void conv_silu_k(
    const float* __restrict__ xb, const float* __restrict__ cw,
    const float* __restrict__ cb, unsigned short* __restrict__ xch,
    unsigned short* __restrict__ xcl)
{
    int i  = blockIdx.x * 256 + threadIdx.x;  // (bl, d)
    int d  = i & 1023;
    int bl = i >> 10;
    int l  = bl & 255;
    float a = cb[d];
#pragma unroll
    for (int k = 0; k < 4; ++k) {
        int ls = l + k - 3;
        if (ls >= 0) a += xb[(size_t)(bl + k - 3) * 1024 + d] * cw[d * 4 + k];
    }
    float v = a / (1.f + __expf(-a));
    unsigned short hb = f2bf(v);
    xch[i] = hb; xcl[i] = f2bf(v - bfs2f(hb));
}

// ---------------------------------------------------------------------------
// selective scan fused with +xc*D and *silu(z).  (R3/R6-proven structure +
// R10 deferred-output: the serial loop's sub==0 tail previously issued 2
// scattered 16 B global stores + sigmoid + 2 cvt PER STEP (512 tiny stores
// per wave, ~4x write-granule waste, vmcnt backpressure on the recurrence).
// Now: serial loop writes y to LDS (1 masked ds_write); a parallel per-chunk
// epilogue (all 256 threads, 8 slots each) does silu-gating + bf16 split +
// COALESCED stores. Identical ops/order -> bit-identical output.
// 8 threads per channel (2 states each), 3-level shuffle reduce;
// 128 blocks = 4 b x 32 chunks of 32 ch.
// R5: don't restructure thread/channel mapping. R9: don't reg-stage loads.
__global__ __launch_bounds__(256) void scan_k(
    const float* __restrict__ zb,
    const unsigned short* __restrict__ xch, const unsigned short* __restrict__ xcl,
    const unsigned short* __restrict__ xdh, const unsigned short* __restrict__ xdl,
    const float* __restrict__ dt, const float* __restrict__ Alog,
    const float* __restrict__ Dp,
    unsigned short* __restrict__ ygh, unsigned short* __restrict__ ygl)
{
    __shared__ float sdt[2048], sxc[2048], szz[2048], sbc[2048], sy[2048]; // 40 KB
    __shared__ float sDp[32];
    int b   = blockIdx.x >> 5;
    int d0  = (blockIdx.x & 31) << 5;
    int ch  = threadIdx.x >> 3;           // channel within chunk (0..31)
    int d   = d0 + ch;
    int sub = threadIdx.x & 7;
    int j0  = sub * 2;                    // this thread's first state idx
    float An[2], hst[2] = {0.f, 0.f};
    An[0] = -__expf(Alog[d * 16 + j0]);
    An[1] = -__expf(Alog[d * 16 + j0 + 1]);
    if (threadIdx.x < 32) sDp[threadIdx.x] = Dp[d0 + threadIdx.x];
    int   bl0 = b * 256;

    for (int c = 0; c < 4; ++c) {
        __syncthreads();                  // also covers sDp (c==0) and prior
                                          // chunk's epilogue reads of sxc/szz/sy
#pragma unroll
        for (int it = 0; it < 8; ++it) {
            int j2 = it * 256 + threadIdx.x;
            int ll = j2 >> 5, dd = j2 & 31;
            size_t row = (size_t)(bl0 + c * 64 + ll);
            size_t gi  = row * 1024 + d0 + dd;
            sdt[j2] = dt[gi];
            sxc[j2] = bfs2f(xch[gi]) + bfs2f(xcl[gi]);
            szz[j2] = zb[gi];
            size_t bi = row * 64 + 32 + dd;
            sbc[j2] = bfs2f(xdh[bi]) + bfs2f(xdl[bi]);
        }
        __syncthreads();
#pragma unroll 4
        for (int li = 0; li < 64; ++li) {
            float dtv = sdt[li * 32 + ch];
            float xcv = sxc[li * 32 + ch];
            float c1  = dtv * xcv;
            float dA0 = __expf(dtv * An[0]);
            float dA1 = __expf(dtv * An[1]);
            float B0  = sbc[li * 32 + j0],      B1 = sbc[li * 32 + j0 + 1];
            float C0  = sbc[li * 32 + 16 + j0], C1 = sbc[li * 32 + 16 + j0 + 1];
            hst[0] = dA0 * hst[0] + c1 * B0;
            hst[1] = dA1 * hst[1] + c1 * B1;
            float y = hst[0] * C0 + hst[1] * C1;
            y += __shfl_xor(y, 1);
            y += __shfl_xor(y, 2);
            y += __shfl_xor(y, 4);
            if (sub == 0) sy[li * 32 + ch] = y;
        }
        __syncthreads();                  // sy complete
        // parallel gating + coalesced store epilogue (8 slots/thread)
#pragma unroll
        for (int it = 0; it < 8; ++it) {
            int j2 = it * 256 + threadIdx.x;
            int ll = j2 >> 5, dd = j2 & 31;
            float y   = sy[j2];
            float xcv = sxc[j2];
            float zv  = szz[j2];
            float sg  = zv / (1.f + __expf(-zv));
            float v   = (y + xcv * sDp[dd]) * sg;
            unsigned short hb = f2bf(v);
            size_t o = (size_t)(bl0 + c * 64 + ll) * 1024 + d0 + dd;
            ygh[o] = hb; ygl[o] = f2bf(v - bfs2f(hb));
        }
    }
}

// ---------------------------------------------------------------------------
// LayerNorm of hlast (4 x 512) -> hn
__global__ __launch_bounds__(512) void ln_k(
    const float* __restrict__ hlast, const float* __restrict__ g,
    const float* __restrict__ bb, float* __restrict__ hn)
{
    __shared__ float red[16];
    int b = blockIdx.x, k = threadIdx.x;
    float x = hlast[b * 512 + k];
    float s = x, s2 = x * x;
#pragma unroll
    for (int m = 32; m; m >>= 1) { s += __shfl_xor(s, m, 64); s2 += __shfl_xor(s2, m, 64); }
    if ((k & 63) == 0) { red[k >> 6] = s; red[8 + (k >> 6)] = s2; }
    __syncthreads();
    float ts = 0.f, ts2 = 0.f;
#pragma unroll
    for (int j = 0; j < 8; ++j) { ts += red[j]; ts2 += red[8 + j]; }
    float mu   = ts * (1.f / 512.f);
    float var  = ts2 * (1.f / 512.f) - mu * mu;
    float rstd = rsqrtf(var + 1e-5f);
    hn[b * 512 + k] = (x - mu) * rstd * g[k] + bb[k];
}

// final: out(4,16384) = hn(4,512) @ out_w(16384,512)^T + out_b  (fp32)
__global__ __launch_bounds__(256) void final_k(
    const float* __restrict__ hn, const float* __restrict__ W,
    const float* __restrict__ ob, float* __restrict__ out)
{
    int wid = threadIdx.x >> 6, lane = threadIdx.x & 63;
    float a[4][8];
#pragma unroll
    for (int b2 = 0; b2 < 4; ++b2) {
        float4 v0 = *(const float4*)&hn[b2 * 512 + lane * 8];
        float4 v1 = *(const float4*)&hn[b2 * 512 + lane * 8 + 4];
        a[b2][0] = v0.x; a[b2][1] = v0.y; a[b2][2] = v0.z; a[b2][3] = v0.w;
        a[b2][4] = v1.x; a[b2][5] = v1.y; a[b2][6] = v1.z; a[b2][7] = v1.w;
    }
#pragma unroll 1
    for (int it = 0; it < 8; ++it) {
        int n = blockIdx.x * 4 + wid + it * 2048;
        const float* W32 = W + (size_t)n * 512 + lane * 8;
        float4 v0 = *(const float4*)W32;
        float4 v1 = *(const float4*)(W32 + 4);
        float wf[8] = {v0.x, v0.y, v0.z, v0.w, v1.x, v1.y, v1.z, v1.w};
        float s0 = 0.f, s1 = 0.f, s2 = 0.f, s3 = 0.f;
#pragma unroll
        for (int j = 0; j < 8; ++j) {
            s0 += a[0][j] * wf[j]; s1 += a[1][j] * wf[j];
            s2 += a[2][j] * wf[j]; s3 += a[3][j] * wf[j];
        }
#pragma unroll
        for (int m = 32; m; m >>= 1) {
            s0 += __shfl_xor(s0, m, 64); s1 += __shfl_xor(s1, m, 64);
            s2 += __shfl_xor(s2, m, 64); s3 += __shfl_xor(s3, m, 64);
        }
        if (lane == 0) {
            float bv = ob[n];
            out[0 * 16384 + n] = s0 + bv;
            out[1 * 16384 + n] = s1 + bv;
            out[2 * 16384 + n] = s2 + bv;
            out[3 * 16384 + n] = s3 + bv;
        }
    }
}

// ---------------------------------------------------------------------------
extern "C" void kernel_launch(void* const* d_in, const int* in_sizes, int n_in,
                              void* d_out, int out_size, void* d_ws, size_t ws_size,
                              hipStream_t stream)
{
    const float* x      = (const float*)d_in[0];
    const float* in_w   = (const float*)d_in[1];
    const float* in_b   = (const float*)d_in[2];
    const float* ln_g   = (const float*)d_in[3];
    const float* ln_b   = (const float*)d_in[4];
    const float* out_w  = (const float*)d_in[5];
    const float* out_b  = (const float*)d_in[6];
    const float* m_in_w = (const float*)d_in[7];
    const float* conv_w = (const float*)d_in[8];
    const float* conv_b = (const float*)d_in[9];
    const float* xproj_w= (const float*)d_in[10];
    const float* dt_w   = (const float*)d_in[11];
    const float* dt_b   = (const float*)d_in[12];
    const float* A_log  = (const float*)d_in[13];
    const float* D_p    = (const float*)d_in[14];
    const float* m_out_w= (const float*)d_in[15];

    // ---- ws layout, peak 22.1 MB (< proven-safe 23.3 MB) ----
    char* W = (char*)d_ws;
    unsigned short* hplh = (unsigned short*)(W + 0);          // h hi  1 MB
    unsigned short* hpll = (unsigned short*)(W + 1048576);    // h lo  1 MB
    float* hlast = (float*)(W + 2097152);                     // 8 KB
    float* hn    = (float*)(W + 2162688);                     // 8 KB
    float* xbuf  = (float*)(W + 2228224);                     // 4 MB
    float* zbuf  = (float*)(W + 6422528);                     // 4 MB
    unsigned short* xch = (unsigned short*)(W + 10616832);    // 2 MB
    unsigned short* xcl = (unsigned short*)(W + 12713984);    // 2 MB
    float* dtb   = (float*)(W + 14811136);                    // 4 MB
    unsigned short* xdbh  = (unsigned short*)(W + 19005440);  // 128 KB
    unsigned short* xdbl_ = (unsigned short*)(W + 19136512);  // 128 KB
    // aliases (sequencing-safe):
    float* part1 = (float*)(W + 2228224);                     // 16 MB, pre-layer only
    float* partx = (float*)(W + 14811136);                    // 4 MB (16 slices), dead before dtb written
    float* parto = (float*)(W + 6422528);                     // 16 MB (8 slices) over zbuf+xc+dtb+xdb (all dead post-scan)
    unsigned short* ygh = (unsigned short*)(W + 2228224);     // 2 MB over xbuf (dead post-conv)
    unsigned short* ygl = (unsigned short*)(W + 4325376);     // 2 MB

    // h = x @ in_w.T + in_b   (split-K=8; 128x128 tile, 512 threads;
    // SWZ=1 z-per-XCD, DBUF=0 — R7 config, 80-85 us band)
    gemm_k<512,128,128,64,0,0,0,0,1,0><<<dim3(8,4,8),512,0,stream>>>(
        x, nullptr, in_w, nullptr, nullptr, part1, nullptr,
        16384, 16384, 512, 2048, 524288);
    reduce_k<<<2048,256,0,stream>>>(part1, 8, 524288, 524288, in_b, 511,
                                    hplh, hpll, hlast, 9);

    for (int i = 0; i < 4; ++i) {
        const float* iw = m_in_w  + (size_t)i * 1048576;
        const float* cw = conv_w  + (size_t)i * 4096;
        const float* cb = conv_b  + (size_t)i * 1024;
        const float* xw = xproj_w + (size_t)i * 65536;
        const float* dw = dt_w    + (size_t)i * 32768;
        const float* db = dt_b    + (size_t)i * 1024;
        const float* Al = A_log   + (size_t)i * 16384;
        const float* Dp = D_p     + (size_t)i * 1024;
        const float* ow = m_out_w + (size_t)i * 524288;

        // xz = h @ iw.T  (1024x2048, K=512) -> xbuf | zbuf  (R6 config)
        gemm_k<512,64,128,64,1,0,0,1,0,0><<<dim3(16,16,1),512,0,stream>>>(
            hplh, hpll, iw, nullptr, nullptr, xbuf, zbuf, 512, 512, 1024, 512, 0);
        // xc = silu(causal_conv(xbuf)) -> planes
        conv_silu_k<<<4096,256,0,stream>>>(xbuf, cw, cb, xch, xcl);
        // xdbl = xc @ xw.T  (1024x64, K=1024, split-K=16 -> 256 blocks)
        gemm_k<256,64,64,64,1,0,0,0,0,0><<<dim3(16,1,16),256,0,stream>>>(
            xch, xcl, xw, nullptr, nullptr, partx, nullptr, 1024, 1024, 64, 64, 65536);
        reduce_k<<<256,256,0,stream>>>(partx, 16, 65536, 65536, nullptr, 63,
                                       xdbh, xdbl_, nullptr, 6);
        // dt = softplus(xdbl[:, :32] @ dw.T + db)  (1024x1024, K=32, 256 blocks)
        gemm_k<256,64,64,32,1,0,2,0,0,0><<<dim3(16,16,1),256,0,stream>>>(
            xdbh, xdbl_, dw, nullptr, db, dtb, nullptr, 64, 32, 1024, 32, 0);
        // yg = (scan + xc*D) * silu(z) -> planes (128 blocks, deferred-output)
        scan_k<<<128,256,0,stream>>>(zbuf, xch, xcl, xdbh, xdbl_, dtb, Al, Dp,
                                     ygh, ygl);
        // h = yg @ ow.T  (1024x512, K=1024, split-K=8 -> 512 blocks, R6 config)
        gemm_k<512,64,128,64,1,0,0,0,0,0><<<dim3(16,4,8),512,0,stream>>>(
            ygh, ygl, ow, nullptr, nullptr, parto, nullptr, 1024, 1024, 512, 128, 524288);
        reduce_k<<<2048,256,0,stream>>>(parto, 8, 524288, 524288, nullptr, 511,
                                        hplh, hpll, hlast, 9);
    }

    ln_k<<<4,512,0,stream>>>(hlast, ln_g, ln_b, hn);
    final_k<<<512,256,0,stream>>>(hn, out_w, out_b, (float*)d_out);
}